// Round 1
// baseline (125.370 us; speedup 1.0000x reference)
//
#include <hip/hip_runtime.h>
#include <math.h>

#define NS 4096
#define NT 4096
#define RPB 8                        // rows computed per block (reads RPB+2 -> 1.25x amp)
#define CCH 2048                     // columns per block
#define CPT 8                        // columns per thread (256 threads * 8 = 2048)
#define NBLK ((NS / RPB) * (NT / CCH))   // 512 * 2 = 1024 blocks

__device__ __forceinline__ double block_reduce(double v, int tid) {
    #pragma unroll
    for (int off = 32; off > 0; off >>= 1)
        v += __shfl_down(v, off, 64);
    __shared__ double lds[4];
    const int lane = tid & 63, wv = tid >> 6;
    if (lane == 0) lds[wv] = v;
    __syncthreads();
    return lds[0] + lds[1] + lds[2] + lds[3];   // valid in all threads
}

__device__ __forceinline__ void load8(const float* __restrict__ p, float* d) {
    const float4 x0 = *(const float4*)(p);
    const float4 x1 = *(const float4*)(p + 4);
    d[0]=x0.x; d[1]=x0.y; d[2]=x0.z; d[3]=x0.w;
    d[4]=x1.x; d[5]=x1.y; d[6]=x1.z; d[7]=x1.w;
}

// Each block owns 8 consecutive rows x 2048 columns with a rolling 3-row register
// window: reads 10 rows to compute 8 (amplification 1.25x). Thread t owns 8
// contiguous columns. Final cross-block reduction is done by the last-arriving
// block (counter in workspace, zeroed by a 4-byte memset node per launch).
__global__ __launch_bounds__(256) void bs_main(const float* __restrict__ V,
                                               double* __restrict__ part,
                                               unsigned* __restrict__ cnt,
                                               float* __restrict__ out,
                                               double C1, double C2) {
    const int tid = threadIdx.x;
    const int rg  = blockIdx.x >> 1;            // row group   (0..511)
    const int cc  = blockIdx.x & 1;             // column chunk (0..1)
    const int r0  = rg * RPB;
    const int j0  = cc * CCH + tid * CPT;

    const double DU = 1.0 / (double)(NS - 1);
    const double dL = C2 - C1;

    const float INV2DU = 2047.5f;      // 1/(2*DU)
    const float INVDU2 = 16769025.0f;  // 1/DU^2 = 4095^2
    const float INV2DT = 102375.0f;    // 1/(2*DT_NORM)
    const float AL     = 2.5f;         // 2r/sigma^2

    float a[CPT], b[CPT], c[CPT];
    const int rm = (r0 > 0) ? r0 - 1 : 0;
    load8(V + (size_t)rm * NT + j0, a);
    load8(V + (size_t)r0 * NT + j0, b);

    double pde = 0.0, bc = 0.0, tc = 0.0;

    #pragma unroll
    for (int rr = 0; rr < RPB; ++rr) {
        const int r  = r0 + rr;
        const int rn = (r + 1 < NS) ? r + 1 : NS - 1;
        load8(V + (size_t)rn * NT + j0, c);

        // ---- per-row stretch metrics (f64 polynomial -> f32) ----
        const double u   = (double)r * DU;
        const double L   = C2 * u + C1 * (1.0 - u);
        const double S   = 100.0 + 30.0 * (L * L * L / 6.0 + L);
        const double dS  = 30.0 * dL * (0.5 * L * L + 1.0);
        const double d2S = 30.0 * dL * dL * L;
        const float Sn   = (float)(S   / 300.0);
        const float Sun  = (float)(dS  / 300.0);
        const float Suun = (float)(d2S / 300.0);
        const float invSun  = 1.0f / Sun;
        const float invSun3 = invSun * invSun * invSun;
        const float Sn2 = Sn * Sn;
        const float ASn = AL * Sn;

        if (r >= 1 && r <= NS - 2) {
            // horizontal edge neighbors of this thread's 8-column strip (L1/L2 hits)
            const float lf = (j0 > 0)        ? V[(size_t)r * NT + j0 - 1]   : 0.0f;
            const float rt = (j0 + CPT < NT) ? V[(size_t)r * NT + j0 + CPT] : 0.0f;

            float pf = 0.0f;   // f32 row partial; error /n_int at the end -> negligible
            #pragma unroll
            for (int k = 0; k < CPT; ++k) {
                const int j = j0 + k;
                if (j >= 1 && j <= NT - 2) {
                    const float cm = (k == 0)       ? lf : b[k - 1];
                    const float cp = (k == CPT - 1) ? rt : b[k + 1];
                    const float Vu  = (c[k] - a[k]) * INV2DU;
                    const float Vuu = (c[k] - 2.0f * b[k] + a[k]) * INVDU2;
                    const float Vt  = (cp - cm) * INV2DT;
                    const float VS  = Vu * invSun;
                    float VSS = (Vuu * Sun - Vu * Suun) * invSun3;
                    VSS = fminf(fmaxf(VSS, -100.0f), 100.0f);
                    const float res = Vt - Sn2 * VSS - ASn * VS + AL * b[k];
                    pf += res * res;
                }
            }
            pde += (double)pf;
        }

        if (r == NS - 1) {
            // far-field BC at S=Smax over all columns of this row
            #pragma unroll
            for (int k = 0; k < CPT; ++k) {
                const float t   = (float)(j0 + k) * (1.0f / (float)(NT - 1));
                const float tgt = 1.0f - (100.0f / 300.0f) * expf(-0.05f * (1.0f - t));
                const float d   = b[k] - tgt;
                bc += (double)(d * d);
            }
        }

        if (j0 + CPT == NT) {
            // terminal condition element V[r, NT-1] == b[CPT-1]
            const float ui = (float)u;
            const float x  = 50.0f * (ui - 100.0f / 300.0f);
            const float sp = fmaxf(x, 0.0f) + log1pf(expf(-fabsf(x)));
            const float payoff = sp * (1.0f / 50.0f);
            const float d  = b[CPT - 1] - payoff;
            const float ad = fabsf(d);
            tc += (double)((ad < 0.01f) ? 0.5f * d * d : 0.01f * (ad - 0.005f));
        }

        // roll the window
        #pragma unroll
        for (int k = 0; k < CPT; ++k) { a[k] = b[k]; b[k] = c[k]; }
    }

    const double n_int = (double)(NS - 2) * (double)(NT - 2);
    double contrib = pde * (1.0 / n_int)
                   + bc  * (10.0 / (double)NT)
                   + tc  * (10.0 / (double)NS);

    contrib = block_reduce(contrib, tid);

    // ---- last-block-done cross-block reduction (saves the bs_final launch) ----
    __shared__ int amLast;
    if (tid == 0) {
        part[blockIdx.x] = contrib;
        __threadfence();                               // make part[] globally visible
        const unsigned old = atomicAdd(cnt, 1u);       // device-scope
        amLast = (old == (unsigned)(NBLK - 1));
    }
    __syncthreads();

    if (amLast) {
        double s = 0.0;
        for (int idx = tid; idx < NBLK; idx += 256)
            s += atomicAdd(&part[idx], 0.0);           // device-scope coherent read
        s = block_reduce(s, tid);
        if (tid == 0) out[0] = (float)s;
    }
}

// Host-side faithful port of CubicStretching._solve_depressed_cubic.
static double cubic_root_host(double Q) {
    const double p = 6.0;                 // CHI
    const double q = p * Q;               // CHI * Q
    const double sp = sqrt(p);
    double arg = fabs(q) / (2.0 * p * sp / (3.0 * sqrt(3.0)));
    if (arg < 1.0) arg = 1.0;
    const double c = 2.0 * sp * cosh(acosh(arg) / 3.0);
    return (q >= 0.0) ? -c : c;
}

extern "C" void kernel_launch(void* const* d_in, const int* in_sizes, int n_in,
                              void* d_out, int out_size, void* d_ws, size_t ws_size,
                              hipStream_t stream) {
    const float* V  = (const float*)d_in[0];
    float* out      = (float*)d_out;
    double* part    = (double*)d_ws;                                  // NBLK doubles
    unsigned* cnt   = (unsigned*)((char*)d_ws + NBLK * sizeof(double));

    const double C1 = cubic_root_host((100.0 - 0.0)   / 30.0);
    const double C2 = cubic_root_host((100.0 - 300.0) / 30.0);

    hipMemsetAsync(cnt, 0, sizeof(unsigned), stream);   // zero the arrival counter
    bs_main<<<NBLK, 256, 0, stream>>>(V, part, cnt, out, C1, C2);
}